// Round 9
// baseline (118.774 us; speedup 1.0000x reference)
//
#include <hip/hip_runtime.h>
#include <cstddef>

#define NB    4
#define NTOK  8192
#define DIMX  256
#define NH    8
#define HD    64
#define INNER 512
#define SPLIT 32
#define EPS   1e-5f

typedef __attribute__((ext_vector_type(8))) short short8;
typedef __attribute__((ext_vector_type(4))) float f32x4;

__device__ __forceinline__ unsigned short f2bf(float f) {
  union { float f; unsigned u; } v; v.f = f;
  unsigned r = v.u + 0x7fffu + ((v.u >> 16) & 1u);   // RNE
  return (unsigned short)(r >> 16);
}

__device__ __forceinline__ short8 cvt8(float4 a, float4 b) {
  short8 p;
  p[0] = (short)f2bf(a.x); p[1] = (short)f2bf(a.y);
  p[2] = (short)f2bf(a.z); p[3] = (short)f2bf(a.w);
  p[4] = (short)f2bf(b.x); p[5] = (short)f2bf(b.y);
  p[6] = (short)f2bf(b.z); p[7] = (short)f2bf(b.w);
  return p;
}

// ---------------------------------------------------------------------------
// Wkv [256][1024] fp32 -> wkvT [1024][256] bf16, LDS tile transpose. 64 blks.
// ---------------------------------------------------------------------------
__global__ __launch_bounds__(256) void k_wkvT(
    const float* __restrict__ Wkv, unsigned short* __restrict__ wkvT)
{
  __shared__ unsigned short t[64][68];
  const int tid = threadIdx.x;
  const int r0 = (blockIdx.x & 3) * 64;
  const int c0 = (blockIdx.x >> 2) * 64;
  const int r = tid >> 2;
  const int c4 = (tid & 3) * 16;
#pragma unroll
  for (int j = 0; j < 4; ++j) {
    float4 v = *(const float4*)(Wkv + (size_t)(r0 + r) * (2 * INNER) + c0 + c4 + j * 4);
    t[r][c4 + j * 4 + 0] = f2bf(v.x);
    t[r][c4 + j * 4 + 1] = f2bf(v.y);
    t[r][c4 + j * 4 + 2] = f2bf(v.z);
    t[r][c4 + j * 4 + 3] = f2bf(v.w);
  }
  __syncthreads();
  const int cc = tid >> 2;
  const int rr4 = (tid & 3) * 16;
  short8 o0, o1;
#pragma unroll
  for (int i = 0; i < 8; ++i) o0[i] = (short)t[rr4 + i][cc];
#pragma unroll
  for (int i = 0; i < 8; ++i) o1[i] = (short)t[rr4 + 8 + i][cc];
  unsigned short* dst = wkvT + (size_t)(c0 + cc) * DIMX + r0 + rr4;
  *(short8*)(dst) = o0;
  *(short8*)(dst + 8) = o1;
}

// ---------------------------------------------------------------------------
// dots partials via MFMA. grid = 1024 blocks, 256 threads.
// Per block: 256 tokens = 8 tiles of 32, one (b,h). Round-8 structure
// (wave split 2Mx2N, wave-local stats, dbuf, 1 barrier/tile) with z read
// directly as fp32 and converted during staging (kills the k_pre z pass).
// ---------------------------------------------------------------------------
__global__ __launch_bounds__(256, 2) void k_dots_mfma(
    const float* __restrict__ z, const unsigned short* __restrict__ wkvT,
    float* __restrict__ partial)
{
  const int tid  = threadIdx.x;
  const int lane = tid & 63;
  const int w    = tid >> 6;       // wave 0..3
  const int wm   = w >> 1;         // 0: k-dims, 1: v-dims
  const int wn   = w & 1;          // token half (16 tokens)
  const int l15  = lane & 15;
  const int lg   = lane >> 4;      // 0..3

  const int bid = blockIdx.x;
  const int s = bid & (SPLIT - 1);
  const int h = (bid >> 5) & (NH - 1);
  const int b = bid >> 8;

  __shared__ unsigned short zs[2][32][268];   // dbuf: 32 tok x 256 dims bf16
  __shared__ unsigned short kv2[2][128][36];  // dbuf: 128 dims x 32 tok bf16

  // A-fragments: wkvT slice for this wave's 64 dims, all 8 K-steps.
  short8 awf[4][8];
#pragma unroll
  for (int mf = 0; mf < 4; ++mf) {
    const int dim = wm * 64 + mf * 16 + l15;   // 0..127
    const int gd = (dim < HD) ? (h * HD + dim) : (INNER + h * HD + (dim - HD));
    const unsigned short* base = wkvT + (size_t)gd * DIMX + lg * 8;
#pragma unroll
    for (int kk = 0; kk < 8; ++kk)
      awf[mf][kk] = *(const short8*)(base + kk * 32);
  }

  f32x4 dacc[4];
#pragma unroll
  for (int nf = 0; nf < 4; ++nf) dacc[nf] = (f32x4){0.f, 0.f, 0.f, 0.f};

  // staging: 32 rows, 8 threads/row, 32 fp32 (8 x float4) per thread
  const int zr = tid >> 3;
  const int zc = (tid & 7) * 32;
  const float* zbase = z + ((size_t)b * NTOK + s * 256 + zr) * DIMX + zc;

  // prologue: stage tile 0 into buffer 0
  {
    float4 pre[8];
#pragma unroll
    for (int j = 0; j < 8; ++j) pre[j] = *(const float4*)(zbase + j * 4);
#pragma unroll
    for (int j = 0; j < 4; ++j)
      *(short8*)&zs[0][zr][zc + j * 8] = cvt8(pre[2 * j], pre[2 * j + 1]);
  }
  __syncthreads();

  int cur = 0;
  for (int tile = 0; tile < 8; ++tile) {
    // prefetch next z tile into regs (in flight during phase 1)
    float4 pre[8];
    if (tile < 7) {
      const float* src = zbase + (size_t)(tile + 1) * 32 * DIMX;
#pragma unroll
      for (int j = 0; j < 8; ++j) pre[j] = *(const float4*)(src + j * 4);
    }

    // ---- phase 1: kvT_raw = wkvT_slice @ zT  (M=64 dims/wave, N=16 tok) ----
    f32x4 acc[4];
#pragma unroll
    for (int mf = 0; mf < 4; ++mf) acc[mf] = (f32x4){0.f, 0.f, 0.f, 0.f};

#pragma unroll
    for (int kk = 0; kk < 8; ++kk) {
      short8 bfr = *(const short8*)&zs[cur][wn * 16 + l15][kk * 32 + lg * 8];
#pragma unroll
      for (int mf = 0; mf < 4; ++mf)
        acc[mf] = __builtin_amdgcn_mfma_f32_16x16x32_bf16(
            awf[mf][kk], bfr, acc[mf], 0, 0, 0);
    }

    // ---- per-token stats: wave-local (all 64 dims of this side in-wave) ----
    float a = 0.f, q = 0.f;
#pragma unroll
    for (int mf = 0; mf < 4; ++mf)
#pragma unroll
      for (int r = 0; r < 4; ++r) {
        float v = acc[mf][r];
        a += v; q += v * v;
      }
    a += __shfl_xor(a, 16); a += __shfl_xor(a, 32);
    q += __shfl_xor(q, 16); q += __shfl_xor(q, 32);
    const float mu = a * (1.f / 64.f);
    const float rs = rsqrtf(q * (1.f / 64.f) - mu * mu + EPS);

    // ---- normalize, write kv2[cur] ----
#pragma unroll
    for (int mf = 0; mf < 4; ++mf)
#pragma unroll
      for (int r = 0; r < 4; ++r)
        kv2[cur][wm * 64 + mf * 16 + lg * 4 + r][wn * 16 + l15] =
            f2bf((acc[mf][r] - mu) * rs);

    // stage next z tile (convert fp32->bf16) into zs[cur^1]
    if (tile < 7) {
#pragma unroll
      for (int j = 0; j < 4; ++j)
        *(short8*)&zs[cur ^ 1][zr][zc + j * 8] = cvt8(pre[2 * j], pre[2 * j + 1]);
    }
    __syncthreads();   // kv2[cur] + zs[cur^1] ready

    // ---- phase 3: dots += k'' @ v''^T (contraction over 32 tokens) ----
    {
      short8 a2 = *(const short8*)&kv2[cur][w * 16 + l15][lg * 8];
#pragma unroll
      for (int nf = 0; nf < 4; ++nf) {
        short8 b2 = *(const short8*)&kv2[cur][64 + nf * 16 + l15][lg * 8];
        dacc[nf] = __builtin_amdgcn_mfma_f32_16x16x32_bf16(a2, b2, dacc[nf], 0, 0, 0);
      }
    }
    cur ^= 1;
  }

  float* pb = partial + ((size_t)((b * NH + h) * SPLIT + s)) * 4096;
#pragma unroll
  for (int nf = 0; nf < 4; ++nf)
#pragma unroll
    for (int r = 0; r < 4; ++r)
      pb[(w * 16 + lg * 4 + r) * 64 + nf * 16 + l15] = dacc[nf][r];
}

// ---------------------------------------------------------------------------
// Fused split-reduce + tmp GEMM (replaces k_reduce + k_bdwout):
// drow[4][64] = (1/n2) * sum_s partial rows; tmp[b][r][c] = drow @ Wout.
// grid = NB*128 = 512 blocks.
// ---------------------------------------------------------------------------
__global__ __launch_bounds__(256) void k_bdwout2(
    const float* __restrict__ partial, const float* __restrict__ Wout,
    float* __restrict__ tmp)
{
  const int bid = blockIdx.x;
  const int b = bid >> 7;
  const int r4 = (bid & 127) * 4;
  const int h = r4 >> 6;
  const int c = threadIdx.x;

  __shared__ float drow[4][64];
  {
    const int rr = c >> 6;          // 0..3
    const int j = c & 63;
    const float* p = partial + (size_t)(b * NH + h) * SPLIT * 4096
                   + ((r4 & 63) + rr) * 64 + j;
    float s = 0.f;
#pragma unroll
    for (int i = 0; i < SPLIT; ++i) s += p[(size_t)i * 4096];
    drow[rr][j] = s * (1.f / (float)NTOK);
  }
  __syncthreads();

  float a0 = 0.f, a1 = 0.f, a2 = 0.f, a3 = 0.f;
#pragma unroll 8
  for (int j = 0; j < 64; ++j) {
    const float wv = Wout[(size_t)(h * 64 + j) * DIMX + c];
    a0 += drow[0][j] * wv;
    a1 += drow[1][j] * wv;
    a2 += drow[2][j] * wv;
    a3 += drow[3][j] * wv;
  }
  float* tb = tmp + ((size_t)b * INNER + r4) * DIMX + c;
  tb[0] = a0; tb[DIMX] = a1; tb[2 * DIMX] = a2; tb[3 * DIMX] = a3;
}

// ---------------------------------------------------------------------------
// W_effT[b][c][r] (bf16) = sum_k Wq[r][k] * tmp[b][k][c]
// ---------------------------------------------------------------------------
__global__ __launch_bounds__(256) void k_weff(
    const float* __restrict__ Wq, const float* __restrict__ tmp,
    unsigned short* __restrict__ weffT)
{
  const int bid = blockIdx.x;
  const int b = bid >> 6;
  const int r4 = (bid & 63) * 4;
  const int c = threadIdx.x;
  const float* tb = tmp + (size_t)b * INNER * DIMX + c;
  float a0 = 0.f, a1 = 0.f, a2 = 0.f, a3 = 0.f;
#pragma unroll 8
  for (int k = 0; k < INNER; ++k) {
    const float t = tb[(size_t)k * DIMX];
    a0 += Wq[(size_t)(r4 + 0) * INNER + k] * t;
    a1 += Wq[(size_t)(r4 + 1) * INNER + k] * t;
    a2 += Wq[(size_t)(r4 + 2) * INNER + k] * t;
    a3 += Wq[(size_t)(r4 + 3) * INNER + k] * t;
  }
  unsigned short* wb = weffT + ((size_t)b * DIMX + c) * DIMX + r4;
  wb[0] = f2bf(a0); wb[1] = f2bf(a1); wb[2] = f2bf(a2); wb[3] = f2bf(a3);
}

// ---------------------------------------------------------------------------
// out[b] = x[b] @ W_eff[b] + bout via MFMA, double-buffered LDS W slices.
// grid = NB*128 = 512 blocks, 256 thr. Block: 64 tokens x 256 cols.
// ---------------------------------------------------------------------------
__global__ __launch_bounds__(256) void k_out_mfma(
    const float* __restrict__ x, const unsigned short* __restrict__ weffT,
    const float* __restrict__ bout, float* __restrict__ out)
{
  const int tid  = threadIdx.x;
  const int lane = tid & 63;
  const int w    = tid >> 6;
  const int l15  = lane & 15;
  const int lg   = lane >> 4;

  const int bid = blockIdx.x;
  const int mt = bid & 127;
  const int b  = bid >> 7;
  const int tok0 = mt * 64;

  __shared__ unsigned short wsl[2][256 * 36];   // k-slice: 256 cols x 32 k, pad 36

  // A-fragments: x row (tok0 + w*16 + l15), converted fp32->bf16.
  short8 afr[8];
  {
    const float* xr = x + ((size_t)b * NTOK + tok0 + w * 16 + l15) * DIMX + lg * 8;
#pragma unroll
    for (int kk = 0; kk < 8; ++kk) {
      float4 xa = *(const float4*)(xr + kk * 32);
      float4 xb = *(const float4*)(xr + kk * 32 + 4);
      afr[kk] = cvt8(xa, xb);
    }
  }

  f32x4 acc[16];
#pragma unroll
  for (int nf = 0; nf < 16; ++nf) acc[nf] = (f32x4){0.f, 0.f, 0.f, 0.f};

  const unsigned short* wb = weffT + (size_t)b * DIMX * DIMX + (size_t)tid * DIMX;

  // prologue: stage slice 0
  {
#pragma unroll
    for (int j = 0; j < 4; ++j) {
      short8 g = *(const short8*)(wb + j * 8);
      *(short8*)&wsl[0][tid * 36 + j * 8] = g;
    }
  }
  __syncthreads();

  for (int kk = 0; kk < 8; ++kk) {
    short8 g[4];
    if (kk < 7) {
#pragma unroll
      for (int j = 0; j < 4; ++j)
        g[j] = *(const short8*)(wb + (kk + 1) * 32 + j * 8);
    }
#pragma unroll
    for (int nf = 0; nf < 16; ++nf) {
      short8 b2 = *(const short8*)&wsl[kk & 1][(nf * 16 + l15) * 36 + lg * 8];
      acc[nf] = __builtin_amdgcn_mfma_f32_16x16x32_bf16(afr[kk], b2, acc[nf], 0, 0, 0);
    }
    if (kk < 7) {
#pragma unroll
      for (int j = 0; j < 4; ++j)
        *(short8*)&wsl[(kk + 1) & 1][tid * 36 + j * 8] = g[j];
    }
    __syncthreads();
  }

#pragma unroll
  for (int nf = 0; nf < 16; ++nf) {
    const float bias = bout[nf * 16 + l15];
#pragma unroll
    for (int r = 0; r < 4; ++r) {
      const int row = tok0 + w * 16 + lg * 4 + r;
      out[((size_t)b * NTOK + row) * DIMX + nf * 16 + l15] = acc[nf][r] + bias;
    }
  }
}

// ---------------------------------------------------------------------------
extern "C" void kernel_launch(void* const* d_in, const int* in_sizes, int n_in,
                              void* d_out, int out_size, void* d_ws, size_t ws_size,
                              hipStream_t stream) {
  const float* x    = (const float*)d_in[0];
  const float* z    = (const float*)d_in[1];
  const float* Wq   = (const float*)d_in[2];
  const float* Wkv  = (const float*)d_in[3];
  const float* Wout = (const float*)d_in[4];
  const float* bout = (const float*)d_in[5];
  float* out = (float*)d_out;

  float* ws  = (float*)d_ws;
  float* tmp = ws;                                            // 524,288 f (2MB)
  unsigned short* wkvT  = (unsigned short*)(tmp + (size_t)NB * INNER * DIMX); // 0.5MB
  unsigned short* weffT = wkvT + (size_t)(2 * INNER) * DIMX;                  // 0.5MB
  // ws total ~3MB

  // partial (1024 x 4096 f32 = 16 MiB) lives in d_out's first half; d_out is
  // 32 MiB and fully rewritten by k_out_mfma at the end (stream-ordered).
  float* partial = (float*)d_out;

  k_wkvT<<<64, 256, 0, stream>>>(Wkv, wkvT);
  k_dots_mfma<<<NB * NH * SPLIT, 256, 0, stream>>>(z, wkvT, partial);
  k_bdwout2<<<NB * 128, 256, 0, stream>>>(partial, Wout, tmp);
  k_weff<<<NB * 64, 256, 0, stream>>>(Wq, tmp, weffT);
  k_out_mfma<<<NB * 128, 256, 0, stream>>>(x, weffT, bout, out);
}

// Round 10
// 103.461 us; speedup vs baseline: 1.1480x; 1.1480x over previous
//
#include <hip/hip_runtime.h>
#include <cstddef>

#define NB    4
#define NTOK  8192
#define DIMX  256
#define NH    8
#define HD    64
#define INNER 512
#define SPLIT 32
#define EPS   1e-5f

typedef __attribute__((ext_vector_type(8))) short short8;
typedef __attribute__((ext_vector_type(4))) float f32x4;

__device__ __forceinline__ unsigned short f2bf(float f) {
  union { float f; unsigned u; } v; v.f = f;
  unsigned r = v.u + 0x7fffu + ((v.u >> 16) & 1u);   // RNE
  return (unsigned short)(r >> 16);
}

// ---------------------------------------------------------------------------
// Fused pre-pass: blocks 0..2047 convert z fp32->bf16 (16 elems/thread);
// blocks 2048..2111 transpose Wkv [256][1024] fp32 -> wkvT [1024][256] bf16.
// ---------------------------------------------------------------------------
__global__ __launch_bounds__(256) void k_pre(
    const float* __restrict__ z, unsigned short* __restrict__ zb,
    const float* __restrict__ Wkv, unsigned short* __restrict__ wkvT)
{
  __shared__ unsigned short t[64][68];
  if (blockIdx.x < 2048) {
    const size_t i = ((size_t)blockIdx.x * 256 + threadIdx.x) * 16;
    float4 a0 = *(const float4*)(z + i);
    float4 a1 = *(const float4*)(z + i + 4);
    float4 a2 = *(const float4*)(z + i + 8);
    float4 a3 = *(const float4*)(z + i + 12);
    short8 p0, p1;
    p0[0] = (short)f2bf(a0.x); p0[1] = (short)f2bf(a0.y);
    p0[2] = (short)f2bf(a0.z); p0[3] = (short)f2bf(a0.w);
    p0[4] = (short)f2bf(a1.x); p0[5] = (short)f2bf(a1.y);
    p0[6] = (short)f2bf(a1.z); p0[7] = (short)f2bf(a1.w);
    p1[0] = (short)f2bf(a2.x); p1[1] = (short)f2bf(a2.y);
    p1[2] = (short)f2bf(a2.z); p1[3] = (short)f2bf(a2.w);
    p1[4] = (short)f2bf(a3.x); p1[5] = (short)f2bf(a3.y);
    p1[6] = (short)f2bf(a3.z); p1[7] = (short)f2bf(a3.w);
    *(short8*)(zb + i) = p0;
    *(short8*)(zb + i + 8) = p1;
  } else {
    const int tid = threadIdx.x;
    const int bb = blockIdx.x - 2048;
    const int r0 = (bb & 3) * 64;
    const int c0 = (bb >> 2) * 64;
    const int r = tid >> 2;
    const int c4 = (tid & 3) * 16;
#pragma unroll
    for (int j = 0; j < 4; ++j) {
      float4 v = *(const float4*)(Wkv + (size_t)(r0 + r) * (2 * INNER) + c0 + c4 + j * 4);
      t[r][c4 + j * 4 + 0] = f2bf(v.x);
      t[r][c4 + j * 4 + 1] = f2bf(v.y);
      t[r][c4 + j * 4 + 2] = f2bf(v.z);
      t[r][c4 + j * 4 + 3] = f2bf(v.w);
    }
    __syncthreads();
    const int cc = tid >> 2;
    const int rr4 = (tid & 3) * 16;
    short8 o0, o1;
#pragma unroll
    for (int i = 0; i < 8; ++i) o0[i] = (short)t[rr4 + i][cc];
#pragma unroll
    for (int i = 0; i < 8; ++i) o1[i] = (short)t[rr4 + 8 + i][cc];
    unsigned short* dst = wkvT + (size_t)(c0 + cc) * DIMX + r0 + rr4;
    *(short8*)(dst) = o0;
    *(short8*)(dst + 8) = o1;
  }
}

// ---------------------------------------------------------------------------
// dots partials via MFMA. grid = NB*NH*SPLIT = 1024 blocks, 256 threads.
// Per block: 256 tokens = 8 tiles of 32, one (b,h). (round-7 proven version)
// ---------------------------------------------------------------------------
__global__ __launch_bounds__(256) void k_dots_mfma(
    const unsigned short* __restrict__ zb, const unsigned short* __restrict__ wkvT,
    float* __restrict__ partial)
{
  const int tid  = threadIdx.x;
  const int lane = tid & 63;
  const int w    = tid >> 6;       // wave 0..3
  const int l15  = lane & 15;
  const int lg   = lane >> 4;      // 0..3

  const int bid = blockIdx.x;
  const int s = bid & (SPLIT - 1);
  const int h = (bid >> 5) & (NH - 1);
  const int b = bid >> 8;

  __shared__ unsigned short zs[32][268];   // 32 tok x 256 dims bf16
  __shared__ unsigned short kv2[128][36];  // 128 dims x 32 tok bf16
  __shared__ float sum1[4][32];
  __shared__ float sum2[4][32];

  // A-fragments: wkvT slice for this wave's 32 dims, all 8 K-steps.
  short8 awf[2][8];
#pragma unroll
  for (int mf = 0; mf < 2; ++mf) {
    const int dim = w * 32 + mf * 16 + l15;
    const int gd = (dim < HD) ? (h * HD + dim) : (INNER + h * HD + (dim - HD));
    const unsigned short* base = wkvT + (size_t)gd * DIMX + lg * 8;
#pragma unroll
    for (int kk = 0; kk < 8; ++kk)
      awf[mf][kk] = *(const short8*)(base + kk * 32);
  }

  f32x4 dacc[4];
#pragma unroll
  for (int nf = 0; nf < 4; ++nf) dacc[nf] = (f32x4){0.f, 0.f, 0.f, 0.f};

  // staging: 32 rows, 8 threads/row, 32 bf16 (4 x short8) per thread
  const int zr = tid >> 3;
  const int zc = (tid & 7) * 32;
  const unsigned short* zbase = zb + ((size_t)b * NTOK + s * 256 + zr) * DIMX + zc;

  // prologue: stage tile 0
  {
    short8 pre[4];
#pragma unroll
    for (int j = 0; j < 4; ++j) pre[j] = *(const short8*)(zbase + j * 8);
#pragma unroll
    for (int j = 0; j < 4; ++j) *(short8*)&zs[zr][zc + j * 8] = pre[j];
  }
  __syncthreads();

  for (int tile = 0; tile < 8; ++tile) {
    // prefetch next z tile into regs (in flight during phase 1)
    short8 pre[4];
    if (tile < 7) {
      const unsigned short* src = zbase + (size_t)(tile + 1) * 32 * DIMX;
#pragma unroll
      for (int j = 0; j < 4; ++j) pre[j] = *(const short8*)(src + j * 8);
    }

    // ---- phase 1: kvT_raw = wkvT_slice @ zT  (M=32 dims/wave, N=32 tok) ----
    f32x4 acc[2][2];
#pragma unroll
    for (int mf = 0; mf < 2; ++mf)
#pragma unroll
      for (int nf = 0; nf < 2; ++nf) acc[mf][nf] = (f32x4){0.f, 0.f, 0.f, 0.f};

#pragma unroll
    for (int kk = 0; kk < 8; ++kk) {
      short8 bfr[2];
#pragma unroll
      for (int nf = 0; nf < 2; ++nf)
        bfr[nf] = *(const short8*)&zs[nf * 16 + l15][kk * 32 + lg * 8];
#pragma unroll
      for (int mf = 0; mf < 2; ++mf)
#pragma unroll
        for (int nf = 0; nf < 2; ++nf)
          acc[mf][nf] = __builtin_amdgcn_mfma_f32_16x16x32_bf16(
              awf[mf][kk], bfr[nf], acc[mf][nf], 0, 0, 0);
    }

    // ---- per-token stats (sum over this wave's 32 dims) ----
    float s1[2], s2[2];
#pragma unroll
    for (int nf = 0; nf < 2; ++nf) {
      float a = 0.f, q = 0.f;
#pragma unroll
      for (int mf = 0; mf < 2; ++mf)
#pragma unroll
        for (int r = 0; r < 4; ++r) {
          float v = acc[mf][nf][r];
          a += v; q += v * v;
        }
      a += __shfl_xor(a, 16); a += __shfl_xor(a, 32);
      q += __shfl_xor(q, 16); q += __shfl_xor(q, 32);
      s1[nf] = a; s2[nf] = q;
    }
    if (lg == 0) {
#pragma unroll
      for (int nf = 0; nf < 2; ++nf) {
        sum1[w][nf * 16 + l15] = s1[nf];
        sum2[w][nf * 16 + l15] = s2[nf];
      }
    }
    __syncthreads();   // B2: sums ready; all waves done reading zs

    // stage next z tile into zs (zs idle until after B3)
    if (tile < 7) {
#pragma unroll
      for (int j = 0; j < 4; ++j) *(short8*)&zs[zr][zc + j * 8] = pre[j];
    }

    // ---- normalize, write kv2 ----
    if (w < 2) {
      // k side: subtract mean only
      const int p = w ^ 1;
      float mu[2];
#pragma unroll
      for (int nf = 0; nf < 2; ++nf)
        mu[nf] = (s1[nf] + sum1[p][nf * 16 + l15]) * (1.f / 64.f);
#pragma unroll
      for (int mf = 0; mf < 2; ++mf)
#pragma unroll
        for (int nf = 0; nf < 2; ++nf)
#pragma unroll
          for (int r = 0; r < 4; ++r)
            kv2[w * 32 + mf * 16 + lg * 4 + r][nf * 16 + l15] =
                f2bf(acc[mf][nf][r] - mu[nf]);
    } else {
      // v side: fold rk*rv into (v - mu_v)
      const int p = w ^ 1;
      float sc[2], ms[2];
#pragma unroll
      for (int nf = 0; nf < 2; ++nf) {
        const int tok = nf * 16 + l15;
        const float t1v = s1[nf] + sum1[p][tok];
        const float t2v = s2[nf] + sum2[p][tok];
        const float muv = t1v * (1.f / 64.f);
        const float rv = rsqrtf(t2v * (1.f / 64.f) - muv * muv + EPS);
        const float t1k = sum1[0][tok] + sum1[1][tok];
        const float t2k = sum2[0][tok] + sum2[1][tok];
        const float muk = t1k * (1.f / 64.f);
        const float rk = rsqrtf(t2k * (1.f / 64.f) - muk * muk + EPS);
        sc[nf] = rk * rv;
        ms[nf] = muv * sc[nf];
      }
#pragma unroll
      for (int mf = 0; mf < 2; ++mf)
#pragma unroll
        for (int nf = 0; nf < 2; ++nf)
#pragma unroll
          for (int r = 0; r < 4; ++r)
            kv2[(w - 2) * 32 + 64 + mf * 16 + lg * 4 + r][nf * 16 + l15] =
                f2bf(fmaf(acc[mf][nf][r], sc[nf], -ms[nf]));
    }
    __syncthreads();   // B3: kv2 + next zs ready

    // ---- phase 3: dots += k'' @ v''^T (contraction over 32 tokens) ----
    {
      short8 a2 = *(const short8*)&kv2[w * 16 + l15][lg * 8];
#pragma unroll
      for (int nf = 0; nf < 4; ++nf) {
        short8 b2 = *(const short8*)&kv2[64 + nf * 16 + l15][lg * 8];
        dacc[nf] = __builtin_amdgcn_mfma_f32_16x16x32_bf16(a2, b2, dacc[nf], 0, 0, 0);
      }
    }
  }

  float* pb = partial + ((size_t)((b * NH + h) * SPLIT + s)) * 4096;
#pragma unroll
  for (int nf = 0; nf < 4; ++nf)
#pragma unroll
    for (int r = 0; r < 4; ++r)
      pb[(w * 16 + lg * 4 + r) * 64 + nf * 16 + l15] = dacc[nf][r];
}

// ---------------------------------------------------------------------------
// Fused split-reduce + tmp GEMM (replaces k_reduce + k_bdwout):
// drow[4][64] = (1/n2) * sum_s partial rows; tmp[b][r][c] = drow @ Wout.
// grid = NB*128 = 512 blocks.
// ---------------------------------------------------------------------------
__global__ __launch_bounds__(256) void k_bdwout2(
    const float* __restrict__ partial, const float* __restrict__ Wout,
    float* __restrict__ tmp)
{
  const int bid = blockIdx.x;
  const int b = bid >> 7;
  const int r4 = (bid & 127) * 4;
  const int h = r4 >> 6;
  const int c = threadIdx.x;

  __shared__ float drow[4][64];
  {
    const int rr = c >> 6;          // 0..3
    const int j = c & 63;
    const float* p = partial + (size_t)(b * NH + h) * SPLIT * 4096
                   + ((r4 & 63) + rr) * 64 + j;
    float s = 0.f;
#pragma unroll
    for (int i = 0; i < SPLIT; ++i) s += p[(size_t)i * 4096];
    drow[rr][j] = s * (1.f / (float)NTOK);
  }
  __syncthreads();

  float a0 = 0.f, a1 = 0.f, a2 = 0.f, a3 = 0.f;
#pragma unroll 8
  for (int j = 0; j < 64; ++j) {
    const float wv = Wout[(size_t)(h * 64 + j) * DIMX + c];
    a0 += drow[0][j] * wv;
    a1 += drow[1][j] * wv;
    a2 += drow[2][j] * wv;
    a3 += drow[3][j] * wv;
  }
  float* tb = tmp + ((size_t)b * INNER + r4) * DIMX + c;
  tb[0] = a0; tb[DIMX] = a1; tb[2 * DIMX] = a2; tb[3 * DIMX] = a3;
}

// ---------------------------------------------------------------------------
// W_effT[b][c][r] (bf16) = sum_k Wq[r][k] * tmp[b][k][c]
// ---------------------------------------------------------------------------
__global__ __launch_bounds__(256) void k_weff(
    const float* __restrict__ Wq, const float* __restrict__ tmp,
    unsigned short* __restrict__ weffT)
{
  const int bid = blockIdx.x;
  const int b = bid >> 6;
  const int r4 = (bid & 63) * 4;
  const int c = threadIdx.x;
  const float* tb = tmp + (size_t)b * INNER * DIMX + c;
  float a0 = 0.f, a1 = 0.f, a2 = 0.f, a3 = 0.f;
#pragma unroll 8
  for (int k = 0; k < INNER; ++k) {
    const float t = tb[(size_t)k * DIMX];
    a0 += Wq[(size_t)(r4 + 0) * INNER + k] * t;
    a1 += Wq[(size_t)(r4 + 1) * INNER + k] * t;
    a2 += Wq[(size_t)(r4 + 2) * INNER + k] * t;
    a3 += Wq[(size_t)(r4 + 3) * INNER + k] * t;
  }
  unsigned short* wb = weffT + ((size_t)b * DIMX + c) * DIMX + r4;
  wb[0] = f2bf(a0); wb[1] = f2bf(a1); wb[2] = f2bf(a2); wb[3] = f2bf(a3);
}

// ---------------------------------------------------------------------------
// out[b] = x[b] @ W_eff[b] + bout via MFMA, double-buffered LDS W slices.
// grid = NB*128 = 512 blocks, 256 thr. Block: 64 tokens x 256 cols.
// ---------------------------------------------------------------------------
__global__ __launch_bounds__(256) void k_out_mfma(
    const float* __restrict__ x, const unsigned short* __restrict__ weffT,
    const float* __restrict__ bout, float* __restrict__ out)
{
  const int tid  = threadIdx.x;
  const int lane = tid & 63;
  const int w    = tid >> 6;
  const int l15  = lane & 15;
  const int lg   = lane >> 4;

  const int bid = blockIdx.x;
  const int mt = bid & 127;
  const int b  = bid >> 7;
  const int tok0 = mt * 64;

  __shared__ unsigned short wsl[2][256 * 36];   // k-slice: 256 cols x 32 k, pad 36

  // A-fragments: x row (tok0 + w*16 + l15), converted fp32->bf16.
  short8 afr[8];
  {
    const float* xr = x + ((size_t)b * NTOK + tok0 + w * 16 + l15) * DIMX + lg * 8;
#pragma unroll
    for (int kk = 0; kk < 8; ++kk) {
      float4 xa = *(const float4*)(xr + kk * 32);
      float4 xb = *(const float4*)(xr + kk * 32 + 4);
      short8 a;
      a[0] = (short)f2bf(xa.x); a[1] = (short)f2bf(xa.y);
      a[2] = (short)f2bf(xa.z); a[3] = (short)f2bf(xa.w);
      a[4] = (short)f2bf(xb.x); a[5] = (short)f2bf(xb.y);
      a[6] = (short)f2bf(xb.z); a[7] = (short)f2bf(xb.w);
      afr[kk] = a;
    }
  }

  f32x4 acc[16];
#pragma unroll
  for (int nf = 0; nf < 16; ++nf) acc[nf] = (f32x4){0.f, 0.f, 0.f, 0.f};

  const unsigned short* wb = weffT + (size_t)b * DIMX * DIMX + (size_t)tid * DIMX;

  // prologue: stage slice 0
  {
#pragma unroll
    for (int j = 0; j < 4; ++j) {
      short8 g = *(const short8*)(wb + j * 8);
      *(short8*)&wsl[0][tid * 36 + j * 8] = g;
    }
  }
  __syncthreads();

  for (int kk = 0; kk < 8; ++kk) {
    short8 g[4];
    if (kk < 7) {
#pragma unroll
      for (int j = 0; j < 4; ++j)
        g[j] = *(const short8*)(wb + (kk + 1) * 32 + j * 8);
    }
#pragma unroll
    for (int nf = 0; nf < 16; ++nf) {
      short8 b2 = *(const short8*)&wsl[kk & 1][(nf * 16 + l15) * 36 + lg * 8];
      acc[nf] = __builtin_amdgcn_mfma_f32_16x16x32_bf16(afr[kk], b2, acc[nf], 0, 0, 0);
    }
    if (kk < 7) {
#pragma unroll
      for (int j = 0; j < 4; ++j)
        *(short8*)&wsl[(kk + 1) & 1][tid * 36 + j * 8] = g[j];
    }
    __syncthreads();
  }

#pragma unroll
  for (int nf = 0; nf < 16; ++nf) {
    const float bias = bout[nf * 16 + l15];
#pragma unroll
    for (int r = 0; r < 4; ++r) {
      const int row = tok0 + w * 16 + lg * 4 + r;
      out[((size_t)b * NTOK + row) * DIMX + nf * 16 + l15] = acc[nf][r] + bias;
    }
  }
}

// ---------------------------------------------------------------------------
extern "C" void kernel_launch(void* const* d_in, const int* in_sizes, int n_in,
                              void* d_out, int out_size, void* d_ws, size_t ws_size,
                              hipStream_t stream) {
  const float* x    = (const float*)d_in[0];
  const float* z    = (const float*)d_in[1];
  const float* Wq   = (const float*)d_in[2];
  const float* Wkv  = (const float*)d_in[3];
  const float* Wout = (const float*)d_in[4];
  const float* bout = (const float*)d_in[5];
  float* out = (float*)d_out;

  float* ws  = (float*)d_ws;
  float* tmp = ws;                                            // 524,288 f (2MB)
  unsigned short* wkvT  = (unsigned short*)(tmp + (size_t)NB * INNER * DIMX); // 0.5MB
  unsigned short* weffT = wkvT + (size_t)(2 * INNER) * DIMX;                  // 0.5MB
  // ws total ~3MB

  // d_out is 32MB and fully rewritten by k_out_mfma at the end:
  //  - first 16MB: z in bf16
  //  - last 16MB : dots split-partials (1024 x 4096 f32)
  unsigned short* zbf = (unsigned short*)d_out;
  float* partial = (float*)((char*)d_out + ((size_t)16 << 20));

  k_pre<<<2112, 256, 0, stream>>>(z, zbf, Wkv, wkvT);
  k_dots_mfma<<<NB * NH * SPLIT, 256, 0, stream>>>(zbf, wkvT, partial);
  k_bdwout2<<<NB * 128, 256, 0, stream>>>(partial, Wout, tmp);
  k_weff<<<NB * 64, 256, 0, stream>>>(Wq, tmp, weffT);
  k_out_mfma<<<NB * 128, 256, 0, stream>>>(x, weffT, bout, out);
}

// Round 11
// 99.185 us; speedup vs baseline: 1.1975x; 1.0431x over previous
//
#include <hip/hip_runtime.h>
#include <cstddef>

#define NB    4
#define NTOK  8192
#define DIMX  256
#define NH    8
#define HD    64
#define INNER 512
#define SPLIT 16
#define EPS   1e-5f

typedef __attribute__((ext_vector_type(8))) short short8;
typedef __attribute__((ext_vector_type(4))) float f32x4;

__device__ __forceinline__ unsigned short f2bf(float f) {
  union { float f; unsigned u; } v; v.f = f;
  unsigned r = v.u + 0x7fffu + ((v.u >> 16) & 1u);   // RNE
  return (unsigned short)(r >> 16);
}

// ---------------------------------------------------------------------------
// Fused pre-pass: blocks 0..2047 convert z fp32->bf16 (16 elems/thread);
// blocks 2048..2111 transpose Wkv [256][1024] fp32 -> wkvT [1024][256] bf16.
// ---------------------------------------------------------------------------
__global__ __launch_bounds__(256) void k_pre(
    const float* __restrict__ z, unsigned short* __restrict__ zb,
    const float* __restrict__ Wkv, unsigned short* __restrict__ wkvT)
{
  __shared__ unsigned short t[64][68];
  if (blockIdx.x < 2048) {
    const size_t i = ((size_t)blockIdx.x * 256 + threadIdx.x) * 16;
    float4 a0 = *(const float4*)(z + i);
    float4 a1 = *(const float4*)(z + i + 4);
    float4 a2 = *(const float4*)(z + i + 8);
    float4 a3 = *(const float4*)(z + i + 12);
    short8 p0, p1;
    p0[0] = (short)f2bf(a0.x); p0[1] = (short)f2bf(a0.y);
    p0[2] = (short)f2bf(a0.z); p0[3] = (short)f2bf(a0.w);
    p0[4] = (short)f2bf(a1.x); p0[5] = (short)f2bf(a1.y);
    p0[6] = (short)f2bf(a1.z); p0[7] = (short)f2bf(a1.w);
    p1[0] = (short)f2bf(a2.x); p1[1] = (short)f2bf(a2.y);
    p1[2] = (short)f2bf(a2.z); p1[3] = (short)f2bf(a2.w);
    p1[4] = (short)f2bf(a3.x); p1[5] = (short)f2bf(a3.y);
    p1[6] = (short)f2bf(a3.z); p1[7] = (short)f2bf(a3.w);
    *(short8*)(zb + i) = p0;
    *(short8*)(zb + i + 8) = p1;
  } else {
    const int tid = threadIdx.x;
    const int bb = blockIdx.x - 2048;
    const int r0 = (bb & 3) * 64;
    const int c0 = (bb >> 2) * 64;
    const int r = tid >> 2;
    const int c4 = (tid & 3) * 16;
#pragma unroll
    for (int j = 0; j < 4; ++j) {
      float4 v = *(const float4*)(Wkv + (size_t)(r0 + r) * (2 * INNER) + c0 + c4 + j * 4);
      t[r][c4 + j * 4 + 0] = f2bf(v.x);
      t[r][c4 + j * 4 + 1] = f2bf(v.y);
      t[r][c4 + j * 4 + 2] = f2bf(v.z);
      t[r][c4 + j * 4 + 3] = f2bf(v.w);
    }
    __syncthreads();
    const int cc = tid >> 2;
    const int rr4 = (tid & 3) * 16;
    short8 o0, o1;
#pragma unroll
    for (int i = 0; i < 8; ++i) o0[i] = (short)t[rr4 + i][cc];
#pragma unroll
    for (int i = 0; i < 8; ++i) o1[i] = (short)t[rr4 + 8 + i][cc];
    unsigned short* dst = wkvT + (size_t)(c0 + cc) * DIMX + r0 + rr4;
    *(short8*)(dst) = o0;
    *(short8*)(dst + 8) = o1;
  }
}

// ---------------------------------------------------------------------------
// dots partials via MFMA. grid = NB*NH*SPLIT = 512 blocks, 256 threads.
// Per block: 512 tokens = 16 tiles of 32, one (b,h). (round-6 proven version)
// ---------------------------------------------------------------------------
__global__ __launch_bounds__(256) void k_dots_mfma(
    const unsigned short* __restrict__ zb, const unsigned short* __restrict__ wkvT,
    float* __restrict__ partial)
{
  const int tid  = threadIdx.x;
  const int lane = tid & 63;
  const int w    = tid >> 6;       // wave 0..3
  const int l15  = lane & 15;
  const int lg   = lane >> 4;      // 0..3

  const int bid = blockIdx.x;
  const int s = bid & (SPLIT - 1);
  const int h = (bid >> 4) & (NH - 1);
  const int b = bid >> 7;

  __shared__ unsigned short zs[32][268];   // 32 tok x 256 dims bf16
  __shared__ unsigned short kv2[128][36];  // 128 dims x 32 tok bf16
  __shared__ float sum1[4][32];
  __shared__ float sum2[4][32];

  // A-fragments: wkvT slice for this wave's 32 dims, all 8 K-steps.
  short8 awf[2][8];
#pragma unroll
  for (int mf = 0; mf < 2; ++mf) {
    const int dim = w * 32 + mf * 16 + l15;
    const int gd = (dim < HD) ? (h * HD + dim) : (INNER + h * HD + (dim - HD));
    const unsigned short* base = wkvT + (size_t)gd * DIMX + lg * 8;
#pragma unroll
    for (int kk = 0; kk < 8; ++kk)
      awf[mf][kk] = *(const short8*)(base + kk * 32);
  }

  f32x4 dacc[4];
#pragma unroll
  for (int nf = 0; nf < 4; ++nf) dacc[nf] = (f32x4){0.f, 0.f, 0.f, 0.f};

  // staging: 32 rows, 8 threads/row, 32 bf16 (4 x short8) per thread
  const int zr = tid >> 3;
  const int zc = (tid & 7) * 32;
  const unsigned short* zbase = zb + ((size_t)b * NTOK + s * 512 + zr) * DIMX + zc;

  // prologue: stage tile 0
  {
    short8 pre[4];
#pragma unroll
    for (int j = 0; j < 4; ++j) pre[j] = *(const short8*)(zbase + j * 8);
#pragma unroll
    for (int j = 0; j < 4; ++j) *(short8*)&zs[zr][zc + j * 8] = pre[j];
  }
  __syncthreads();

  for (int tile = 0; tile < 16; ++tile) {
    // prefetch next z tile into regs (in flight during phase 1)
    short8 pre[4];
    if (tile < 15) {
      const unsigned short* src = zbase + (size_t)(tile + 1) * 32 * DIMX;
#pragma unroll
      for (int j = 0; j < 4; ++j) pre[j] = *(const short8*)(src + j * 8);
    }

    // ---- phase 1: kvT_raw = wkvT_slice @ zT  (M=32 dims/wave, N=32 tok) ----
    f32x4 acc[2][2];
#pragma unroll
    for (int mf = 0; mf < 2; ++mf)
#pragma unroll
      for (int nf = 0; nf < 2; ++nf) acc[mf][nf] = (f32x4){0.f, 0.f, 0.f, 0.f};

#pragma unroll
    for (int kk = 0; kk < 8; ++kk) {
      short8 bfr[2];
#pragma unroll
      for (int nf = 0; nf < 2; ++nf)
        bfr[nf] = *(const short8*)&zs[nf * 16 + l15][kk * 32 + lg * 8];
#pragma unroll
      for (int mf = 0; mf < 2; ++mf)
#pragma unroll
        for (int nf = 0; nf < 2; ++nf)
          acc[mf][nf] = __builtin_amdgcn_mfma_f32_16x16x32_bf16(
              awf[mf][kk], bfr[nf], acc[mf][nf], 0, 0, 0);
    }

    // ---- per-token stats (sum over this wave's 32 dims) ----
    float s1[2], s2[2];
#pragma unroll
    for (int nf = 0; nf < 2; ++nf) {
      float a = 0.f, q = 0.f;
#pragma unroll
      for (int mf = 0; mf < 2; ++mf)
#pragma unroll
        for (int r = 0; r < 4; ++r) {
          float v = acc[mf][nf][r];
          a += v; q += v * v;
        }
      a += __shfl_xor(a, 16); a += __shfl_xor(a, 32);
      q += __shfl_xor(q, 16); q += __shfl_xor(q, 32);
      s1[nf] = a; s2[nf] = q;
    }
    if (lg == 0) {
#pragma unroll
      for (int nf = 0; nf < 2; ++nf) {
        sum1[w][nf * 16 + l15] = s1[nf];
        sum2[w][nf * 16 + l15] = s2[nf];
      }
    }
    __syncthreads();   // B2: sums ready; all waves done reading zs

    // stage next z tile into zs (zs idle until after B3)
    if (tile < 15) {
#pragma unroll
      for (int j = 0; j < 4; ++j) *(short8*)&zs[zr][zc + j * 8] = pre[j];
    }

    // ---- normalize, write kv2 ----
    if (w < 2) {
      // k side: subtract mean only
      const int p = w ^ 1;
      float mu[2];
#pragma unroll
      for (int nf = 0; nf < 2; ++nf)
        mu[nf] = (s1[nf] + sum1[p][nf * 16 + l15]) * (1.f / 64.f);
#pragma unroll
      for (int mf = 0; mf < 2; ++mf)
#pragma unroll
        for (int nf = 0; nf < 2; ++nf)
#pragma unroll
          for (int r = 0; r < 4; ++r)
            kv2[w * 32 + mf * 16 + lg * 4 + r][nf * 16 + l15] =
                f2bf(acc[mf][nf][r] - mu[nf]);
    } else {
      // v side: fold rk*rv into (v - mu_v)
      const int p = w ^ 1;
      float sc[2], ms[2];
#pragma unroll
      for (int nf = 0; nf < 2; ++nf) {
        const int tok = nf * 16 + l15;
        const float t1v = s1[nf] + sum1[p][tok];
        const float t2v = s2[nf] + sum2[p][tok];
        const float muv = t1v * (1.f / 64.f);
        const float rv = rsqrtf(t2v * (1.f / 64.f) - muv * muv + EPS);
        const float t1k = sum1[0][tok] + sum1[1][tok];
        const float t2k = sum2[0][tok] + sum2[1][tok];
        const float muk = t1k * (1.f / 64.f);
        const float rk = rsqrtf(t2k * (1.f / 64.f) - muk * muk + EPS);
        sc[nf] = rk * rv;
        ms[nf] = muv * sc[nf];
      }
#pragma unroll
      for (int mf = 0; mf < 2; ++mf)
#pragma unroll
        for (int nf = 0; nf < 2; ++nf)
#pragma unroll
          for (int r = 0; r < 4; ++r)
            kv2[(w - 2) * 32 + 64 + mf * 16 + lg * 4 + r][nf * 16 + l15] =
                f2bf(fmaf(acc[mf][nf][r], sc[nf], -ms[nf]));
    }
    __syncthreads();   // B3: kv2 + next zs ready

    // ---- phase 3: dots += k'' @ v''^T (contraction over 32 tokens) ----
    {
      short8 a2 = *(const short8*)&kv2[w * 16 + l15][lg * 8];
#pragma unroll
      for (int nf = 0; nf < 4; ++nf) {
        short8 b2 = *(const short8*)&kv2[64 + nf * 16 + l15][lg * 8];
        dacc[nf] = __builtin_amdgcn_mfma_f32_16x16x32_bf16(a2, b2, dacc[nf], 0, 0, 0);
      }
    }
  }

  float* pb = partial + ((size_t)((b * NH + h) * SPLIT + s)) * 4096;
#pragma unroll
  for (int nf = 0; nf < 4; ++nf)
#pragma unroll
    for (int r = 0; r < 4; ++r)
      pb[(w * 16 + lg * 4 + r) * 64 + nf * 16 + l15] = dacc[nf][r];
}

// ---------------------------------------------------------------------------
// Fused split-reduce + tmp GEMM (replaces k_reduce + k_bdwout):
// drow[4][64] = (1/n2) * sum_s partial rows; tmp[b][r][c] = drow @ Wout.
// grid = NB*128 = 512 blocks.
// ---------------------------------------------------------------------------
__global__ __launch_bounds__(256) void k_bdwout2(
    const float* __restrict__ partial, const float* __restrict__ Wout,
    float* __restrict__ tmp)
{
  const int bid = blockIdx.x;
  const int b = bid >> 7;
  const int r4 = (bid & 127) * 4;
  const int h = r4 >> 6;
  const int c = threadIdx.x;

  __shared__ float drow[4][64];
  {
    const int rr = c >> 6;          // 0..3
    const int j = c & 63;
    const float* p = partial + (size_t)(b * NH + h) * SPLIT * 4096
                   + ((r4 & 63) + rr) * 64 + j;
    float s = 0.f;
#pragma unroll
    for (int i = 0; i < SPLIT; ++i) s += p[(size_t)i * 4096];
    drow[rr][j] = s * (1.f / (float)NTOK);
  }
  __syncthreads();

  float a0 = 0.f, a1 = 0.f, a2 = 0.f, a3 = 0.f;
#pragma unroll 8
  for (int j = 0; j < 64; ++j) {
    const float wv = Wout[(size_t)(h * 64 + j) * DIMX + c];
    a0 += drow[0][j] * wv;
    a1 += drow[1][j] * wv;
    a2 += drow[2][j] * wv;
    a3 += drow[3][j] * wv;
  }
  float* tb = tmp + ((size_t)b * INNER + r4) * DIMX + c;
  tb[0] = a0; tb[DIMX] = a1; tb[2 * DIMX] = a2; tb[3 * DIMX] = a3;
}

// ---------------------------------------------------------------------------
// W_effT[b][c][r] (bf16) = sum_k Wq[r][k] * tmp[b][k][c]
// ---------------------------------------------------------------------------
__global__ __launch_bounds__(256) void k_weff(
    const float* __restrict__ Wq, const float* __restrict__ tmp,
    unsigned short* __restrict__ weffT)
{
  const int bid = blockIdx.x;
  const int b = bid >> 6;
  const int r4 = (bid & 63) * 4;
  const int c = threadIdx.x;
  const float* tb = tmp + (size_t)b * INNER * DIMX + c;
  float a0 = 0.f, a1 = 0.f, a2 = 0.f, a3 = 0.f;
#pragma unroll 8
  for (int k = 0; k < INNER; ++k) {
    const float t = tb[(size_t)k * DIMX];
    a0 += Wq[(size_t)(r4 + 0) * INNER + k] * t;
    a1 += Wq[(size_t)(r4 + 1) * INNER + k] * t;
    a2 += Wq[(size_t)(r4 + 2) * INNER + k] * t;
    a3 += Wq[(size_t)(r4 + 3) * INNER + k] * t;
  }
  unsigned short* wb = weffT + ((size_t)b * DIMX + c) * DIMX + r4;
  wb[0] = f2bf(a0); wb[1] = f2bf(a1); wb[2] = f2bf(a2); wb[3] = f2bf(a3);
}

// ---------------------------------------------------------------------------
// out[b] = x[b] @ W_eff[b] + bout via MFMA, double-buffered LDS W slices.
// grid = NB*128 = 512 blocks, 256 thr. Block: 64 tokens x 256 cols.
// ---------------------------------------------------------------------------
__global__ __launch_bounds__(256) void k_out_mfma(
    const float* __restrict__ x, const unsigned short* __restrict__ weffT,
    const float* __restrict__ bout, float* __restrict__ out)
{
  const int tid  = threadIdx.x;
  const int lane = tid & 63;
  const int w    = tid >> 6;
  const int l15  = lane & 15;
  const int lg   = lane >> 4;

  const int bid = blockIdx.x;
  const int mt = bid & 127;
  const int b  = bid >> 7;
  const int tok0 = mt * 64;

  __shared__ unsigned short wsl[2][256 * 36];   // k-slice: 256 cols x 32 k, pad 36

  // A-fragments: x row (tok0 + w*16 + l15), converted fp32->bf16.
  short8 afr[8];
  {
    const float* xr = x + ((size_t)b * NTOK + tok0 + w * 16 + l15) * DIMX + lg * 8;
#pragma unroll
    for (int kk = 0; kk < 8; ++kk) {
      float4 xa = *(const float4*)(xr + kk * 32);
      float4 xb = *(const float4*)(xr + kk * 32 + 4);
      short8 a;
      a[0] = (short)f2bf(xa.x); a[1] = (short)f2bf(xa.y);
      a[2] = (short)f2bf(xa.z); a[3] = (short)f2bf(xa.w);
      a[4] = (short)f2bf(xb.x); a[5] = (short)f2bf(xb.y);
      a[6] = (short)f2bf(xb.z); a[7] = (short)f2bf(xb.w);
      afr[kk] = a;
    }
  }

  f32x4 acc[16];
#pragma unroll
  for (int nf = 0; nf < 16; ++nf) acc[nf] = (f32x4){0.f, 0.f, 0.f, 0.f};

  const unsigned short* wb = weffT + (size_t)b * DIMX * DIMX + (size_t)tid * DIMX;

  // prologue: stage slice 0
  {
#pragma unroll
    for (int j = 0; j < 4; ++j) {
      short8 g = *(const short8*)(wb + j * 8);
      *(short8*)&wsl[0][tid * 36 + j * 8] = g;
    }
  }
  __syncthreads();

  for (int kk = 0; kk < 8; ++kk) {
    short8 g[4];
    if (kk < 7) {
#pragma unroll
      for (int j = 0; j < 4; ++j)
        g[j] = *(const short8*)(wb + (kk + 1) * 32 + j * 8);
    }
#pragma unroll
    for (int nf = 0; nf < 16; ++nf) {
      short8 b2 = *(const short8*)&wsl[kk & 1][(nf * 16 + l15) * 36 + lg * 8];
      acc[nf] = __builtin_amdgcn_mfma_f32_16x16x32_bf16(afr[kk], b2, acc[nf], 0, 0, 0);
    }
    if (kk < 7) {
#pragma unroll
      for (int j = 0; j < 4; ++j)
        *(short8*)&wsl[(kk + 1) & 1][tid * 36 + j * 8] = g[j];
    }
    __syncthreads();
  }

#pragma unroll
  for (int nf = 0; nf < 16; ++nf) {
    const float bias = bout[nf * 16 + l15];
#pragma unroll
    for (int r = 0; r < 4; ++r) {
      const int row = tok0 + w * 16 + lg * 4 + r;
      out[((size_t)b * NTOK + row) * DIMX + nf * 16 + l15] = acc[nf][r] + bias;
    }
  }
}

// ---------------------------------------------------------------------------
extern "C" void kernel_launch(void* const* d_in, const int* in_sizes, int n_in,
                              void* d_out, int out_size, void* d_ws, size_t ws_size,
                              hipStream_t stream) {
  const float* x    = (const float*)d_in[0];
  const float* z    = (const float*)d_in[1];
  const float* Wq   = (const float*)d_in[2];
  const float* Wkv  = (const float*)d_in[3];
  const float* Wout = (const float*)d_in[4];
  const float* bout = (const float*)d_in[5];
  float* out = (float*)d_out;

  float* ws  = (float*)d_ws;
  float* tmp = ws;                                            // 524,288 f (2MB)
  unsigned short* wkvT  = (unsigned short*)(tmp + (size_t)NB * INNER * DIMX); // 0.5MB
  unsigned short* weffT = wkvT + (size_t)(2 * INNER) * DIMX;                  // 0.5MB
  // ws total ~3MB

  // d_out is 32MB and fully rewritten by k_out_mfma at the end:
  //  - first 16MB: z in bf16
  //  - next 8MB  : dots split-partials (512 x 4096 f32)
  unsigned short* zbf = (unsigned short*)d_out;
  float* partial = (float*)((char*)d_out + ((size_t)16 << 20));

  k_pre<<<2112, 256, 0, stream>>>(z, zbf, Wkv, wkvT);
  k_dots_mfma<<<NB * NH * SPLIT, 256, 0, stream>>>(zbf, wkvT, partial);
  k_bdwout2<<<NB * 128, 256, 0, stream>>>(partial, Wout, tmp);
  k_weff<<<NB * 64, 256, 0, stream>>>(Wq, tmp, weffT);
  k_out_mfma<<<NB * 128, 256, 0, stream>>>(x, weffT, bout, out);
}

// Round 12
// 92.154 us; speedup vs baseline: 1.2889x; 1.0763x over previous
//
#include <hip/hip_runtime.h>
#include <cstddef>

#define NB    4
#define NTOK  8192
#define DIMX  256
#define NH    8
#define HD    64
#define INNER 512
#define SPLIT 16
#define EPS   1e-5f

typedef __attribute__((ext_vector_type(8))) short short8;
typedef __attribute__((ext_vector_type(4))) float f32x4;

__device__ __forceinline__ unsigned short f2bf(float f) {
  union { float f; unsigned u; } v; v.f = f;
  unsigned r = v.u + 0x7fffu + ((v.u >> 16) & 1u);   // RNE
  return (unsigned short)(r >> 16);
}

// ---------------------------------------------------------------------------
// Fused pre-pass: blocks 0..2047 convert z fp32->bf16 (16 elems/thread);
// blocks 2048..2111 transpose Wkv [256][1024] fp32 -> wkvT [1024][256] bf16.
// ---------------------------------------------------------------------------
__global__ __launch_bounds__(256) void k_pre(
    const float* __restrict__ z, unsigned short* __restrict__ zb,
    const float* __restrict__ Wkv, unsigned short* __restrict__ wkvT)
{
  __shared__ unsigned short t[64][68];
  if (blockIdx.x < 2048) {
    const size_t i = ((size_t)blockIdx.x * 256 + threadIdx.x) * 16;
    float4 a0 = *(const float4*)(z + i);
    float4 a1 = *(const float4*)(z + i + 4);
    float4 a2 = *(const float4*)(z + i + 8);
    float4 a3 = *(const float4*)(z + i + 12);
    short8 p0, p1;
    p0[0] = (short)f2bf(a0.x); p0[1] = (short)f2bf(a0.y);
    p0[2] = (short)f2bf(a0.z); p0[3] = (short)f2bf(a0.w);
    p0[4] = (short)f2bf(a1.x); p0[5] = (short)f2bf(a1.y);
    p0[6] = (short)f2bf(a1.z); p0[7] = (short)f2bf(a1.w);
    p1[0] = (short)f2bf(a2.x); p1[1] = (short)f2bf(a2.y);
    p1[2] = (short)f2bf(a2.z); p1[3] = (short)f2bf(a2.w);
    p1[4] = (short)f2bf(a3.x); p1[5] = (short)f2bf(a3.y);
    p1[6] = (short)f2bf(a3.z); p1[7] = (short)f2bf(a3.w);
    *(short8*)(zb + i) = p0;
    *(short8*)(zb + i + 8) = p1;
  } else {
    const int tid = threadIdx.x;
    const int bb = blockIdx.x - 2048;
    const int r0 = (bb & 3) * 64;
    const int c0 = (bb >> 2) * 64;
    const int r = tid >> 2;
    const int c4 = (tid & 3) * 16;
#pragma unroll
    for (int j = 0; j < 4; ++j) {
      float4 v = *(const float4*)(Wkv + (size_t)(r0 + r) * (2 * INNER) + c0 + c4 + j * 4);
      t[r][c4 + j * 4 + 0] = f2bf(v.x);
      t[r][c4 + j * 4 + 1] = f2bf(v.y);
      t[r][c4 + j * 4 + 2] = f2bf(v.z);
      t[r][c4 + j * 4 + 3] = f2bf(v.w);
    }
    __syncthreads();
    const int cc = tid >> 2;
    const int rr4 = (tid & 3) * 16;
    short8 o0, o1;
#pragma unroll
    for (int i = 0; i < 8; ++i) o0[i] = (short)t[rr4 + i][cc];
#pragma unroll
    for (int i = 0; i < 8; ++i) o1[i] = (short)t[rr4 + 8 + i][cc];
    unsigned short* dst = wkvT + (size_t)(c0 + cc) * DIMX + r0 + rr4;
    *(short8*)(dst) = o0;
    *(short8*)(dst + 8) = o1;
  }
}

// ---------------------------------------------------------------------------
// dots partials via MFMA. grid = NB*NH*SPLIT = 512 blocks, 256 threads.
// Per block: 512 tokens = 16 tiles of 32, one (b,h). (round-6/11 proven)
// ---------------------------------------------------------------------------
__global__ __launch_bounds__(256) void k_dots_mfma(
    const unsigned short* __restrict__ zb, const unsigned short* __restrict__ wkvT,
    float* __restrict__ partial)
{
  const int tid  = threadIdx.x;
  const int lane = tid & 63;
  const int w    = tid >> 6;       // wave 0..3
  const int l15  = lane & 15;
  const int lg   = lane >> 4;      // 0..3

  const int bid = blockIdx.x;
  const int s = bid & (SPLIT - 1);
  const int h = (bid >> 4) & (NH - 1);
  const int b = bid >> 7;

  __shared__ unsigned short zs[32][268];   // 32 tok x 256 dims bf16
  __shared__ unsigned short kv2[128][36];  // 128 dims x 32 tok bf16
  __shared__ float sum1[4][32];
  __shared__ float sum2[4][32];

  // A-fragments: wkvT slice for this wave's 32 dims, all 8 K-steps.
  short8 awf[2][8];
#pragma unroll
  for (int mf = 0; mf < 2; ++mf) {
    const int dim = w * 32 + mf * 16 + l15;
    const int gd = (dim < HD) ? (h * HD + dim) : (INNER + h * HD + (dim - HD));
    const unsigned short* base = wkvT + (size_t)gd * DIMX + lg * 8;
#pragma unroll
    for (int kk = 0; kk < 8; ++kk)
      awf[mf][kk] = *(const short8*)(base + kk * 32);
  }

  f32x4 dacc[4];
#pragma unroll
  for (int nf = 0; nf < 4; ++nf) dacc[nf] = (f32x4){0.f, 0.f, 0.f, 0.f};

  // staging: 32 rows, 8 threads/row, 32 bf16 (4 x short8) per thread
  const int zr = tid >> 3;
  const int zc = (tid & 7) * 32;
  const unsigned short* zbase = zb + ((size_t)b * NTOK + s * 512 + zr) * DIMX + zc;

  // prologue: stage tile 0
  {
    short8 pre[4];
#pragma unroll
    for (int j = 0; j < 4; ++j) pre[j] = *(const short8*)(zbase + j * 8);
#pragma unroll
    for (int j = 0; j < 4; ++j) *(short8*)&zs[zr][zc + j * 8] = pre[j];
  }
  __syncthreads();

  for (int tile = 0; tile < 16; ++tile) {
    // prefetch next z tile into regs (in flight during phase 1)
    short8 pre[4];
    if (tile < 15) {
      const unsigned short* src = zbase + (size_t)(tile + 1) * 32 * DIMX;
#pragma unroll
      for (int j = 0; j < 4; ++j) pre[j] = *(const short8*)(src + j * 8);
    }

    // ---- phase 1: kvT_raw = wkvT_slice @ zT  (M=32 dims/wave, N=32 tok) ----
    f32x4 acc[2][2];
#pragma unroll
    for (int mf = 0; mf < 2; ++mf)
#pragma unroll
      for (int nf = 0; nf < 2; ++nf) acc[mf][nf] = (f32x4){0.f, 0.f, 0.f, 0.f};

#pragma unroll
    for (int kk = 0; kk < 8; ++kk) {
      short8 bfr[2];
#pragma unroll
      for (int nf = 0; nf < 2; ++nf)
        bfr[nf] = *(const short8*)&zs[nf * 16 + l15][kk * 32 + lg * 8];
#pragma unroll
      for (int mf = 0; mf < 2; ++mf)
#pragma unroll
        for (int nf = 0; nf < 2; ++nf)
          acc[mf][nf] = __builtin_amdgcn_mfma_f32_16x16x32_bf16(
              awf[mf][kk], bfr[nf], acc[mf][nf], 0, 0, 0);
    }

    // ---- per-token stats (sum over this wave's 32 dims) ----
    float s1[2], s2[2];
#pragma unroll
    for (int nf = 0; nf < 2; ++nf) {
      float a = 0.f, q = 0.f;
#pragma unroll
      for (int mf = 0; mf < 2; ++mf)
#pragma unroll
        for (int r = 0; r < 4; ++r) {
          float v = acc[mf][nf][r];
          a += v; q += v * v;
        }
      a += __shfl_xor(a, 16); a += __shfl_xor(a, 32);
      q += __shfl_xor(q, 16); q += __shfl_xor(q, 32);
      s1[nf] = a; s2[nf] = q;
    }
    if (lg == 0) {
#pragma unroll
      for (int nf = 0; nf < 2; ++nf) {
        sum1[w][nf * 16 + l15] = s1[nf];
        sum2[w][nf * 16 + l15] = s2[nf];
      }
    }
    __syncthreads();   // B2: sums ready; all waves done reading zs

    // stage next z tile into zs (zs idle until after B3)
    if (tile < 15) {
#pragma unroll
      for (int j = 0; j < 4; ++j) *(short8*)&zs[zr][zc + j * 8] = pre[j];
    }

    // ---- normalize, write kv2 ----
    if (w < 2) {
      // k side: subtract mean only
      const int p = w ^ 1;
      float mu[2];
#pragma unroll
      for (int nf = 0; nf < 2; ++nf)
        mu[nf] = (s1[nf] + sum1[p][nf * 16 + l15]) * (1.f / 64.f);
#pragma unroll
      for (int mf = 0; mf < 2; ++mf)
#pragma unroll
        for (int nf = 0; nf < 2; ++nf)
#pragma unroll
          for (int r = 0; r < 4; ++r)
            kv2[w * 32 + mf * 16 + lg * 4 + r][nf * 16 + l15] =
                f2bf(acc[mf][nf][r] - mu[nf]);
    } else {
      // v side: fold rk*rv into (v - mu_v)
      const int p = w ^ 1;
      float sc[2], ms[2];
#pragma unroll
      for (int nf = 0; nf < 2; ++nf) {
        const int tok = nf * 16 + l15;
        const float t1v = s1[nf] + sum1[p][tok];
        const float t2v = s2[nf] + sum2[p][tok];
        const float muv = t1v * (1.f / 64.f);
        const float rv = rsqrtf(t2v * (1.f / 64.f) - muv * muv + EPS);
        const float t1k = sum1[0][tok] + sum1[1][tok];
        const float t2k = sum2[0][tok] + sum2[1][tok];
        const float muk = t1k * (1.f / 64.f);
        const float rk = rsqrtf(t2k * (1.f / 64.f) - muk * muk + EPS);
        sc[nf] = rk * rv;
        ms[nf] = muv * sc[nf];
      }
#pragma unroll
      for (int mf = 0; mf < 2; ++mf)
#pragma unroll
        for (int nf = 0; nf < 2; ++nf)
#pragma unroll
          for (int r = 0; r < 4; ++r)
            kv2[(w - 2) * 32 + 64 + mf * 16 + lg * 4 + r][nf * 16 + l15] =
                f2bf(fmaf(acc[mf][nf][r], sc[nf], -ms[nf]));
    }
    __syncthreads();   // B3: kv2 + next zs ready

    // ---- phase 3: dots += k'' @ v''^T (contraction over 32 tokens) ----
    {
      short8 a2 = *(const short8*)&kv2[w * 16 + l15][lg * 8];
#pragma unroll
      for (int nf = 0; nf < 4; ++nf) {
        short8 b2 = *(const short8*)&kv2[64 + nf * 16 + l15][lg * 8];
        dacc[nf] = __builtin_amdgcn_mfma_f32_16x16x32_bf16(a2, b2, dacc[nf], 0, 0, 0);
      }
    }
  }

  float* pb = partial + ((size_t)((b * NH + h) * SPLIT + s)) * 4096;
#pragma unroll
  for (int nf = 0; nf < 4; ++nf)
#pragma unroll
    for (int r = 0; r < 4; ++r)
      pb[(w * 16 + lg * 4 + r) * 64 + nf * 16 + l15] = dacc[nf][r];
}

// ---------------------------------------------------------------------------
// Fused split-reduce + tmp GEMM:
// drow[4][64] = (1/n2) * sum_s partial rows; tmp[b][r][c] = drow @ Wout.
// grid = NB*128 = 512 blocks.
// ---------------------------------------------------------------------------
__global__ __launch_bounds__(256) void k_bdwout2(
    const float* __restrict__ partial, const float* __restrict__ Wout,
    float* __restrict__ tmp)
{
  const int bid = blockIdx.x;
  const int b = bid >> 7;
  const int r4 = (bid & 127) * 4;
  const int h = r4 >> 6;
  const int c = threadIdx.x;

  __shared__ float drow[4][64];
  {
    const int rr = c >> 6;          // 0..3
    const int j = c & 63;
    const float* p = partial + (size_t)(b * NH + h) * SPLIT * 4096
                   + ((r4 & 63) + rr) * 64 + j;
    float s = 0.f;
#pragma unroll
    for (int i = 0; i < SPLIT; ++i) s += p[(size_t)i * 4096];
    drow[rr][j] = s * (1.f / (float)NTOK);
  }
  __syncthreads();

  float a0 = 0.f, a1 = 0.f, a2 = 0.f, a3 = 0.f;
#pragma unroll 8
  for (int j = 0; j < 64; ++j) {
    const float wv = Wout[(size_t)(h * 64 + j) * DIMX + c];
    a0 += drow[0][j] * wv;
    a1 += drow[1][j] * wv;
    a2 += drow[2][j] * wv;
    a3 += drow[3][j] * wv;
  }
  float* tb = tmp + ((size_t)b * INNER + r4) * DIMX + c;
  tb[0] = a0; tb[DIMX] = a1; tb[2 * DIMX] = a2; tb[3 * DIMX] = a3;
}

// ---------------------------------------------------------------------------
// W_effT[b][c][r] (bf16) = sum_k Wq[r][k] * tmp[b][k][c]
// grid = NB*128 blocks (2 rows each), 256 threads (c).
// ---------------------------------------------------------------------------
__global__ __launch_bounds__(256) void k_weff(
    const float* __restrict__ Wq, const float* __restrict__ tmp,
    unsigned short* __restrict__ weffT)
{
  const int bid = blockIdx.x;
  const int b = bid >> 7;
  const int r2 = (bid & 127) * 2;
  const int c = threadIdx.x;
  const float* tb = tmp + (size_t)b * INNER * DIMX + c;
  float a0 = 0.f, a1 = 0.f;
#pragma unroll 16
  for (int k = 0; k < INNER; ++k) {
    const float t = tb[(size_t)k * DIMX];
    a0 += Wq[(size_t)(r2 + 0) * INNER + k] * t;
    a1 += Wq[(size_t)(r2 + 1) * INNER + k] * t;
  }
  unsigned short* wb = weffT + ((size_t)b * DIMX + c) * DIMX + r2;
  wb[0] = f2bf(a0); wb[1] = f2bf(a1);
}

// ---------------------------------------------------------------------------
// out[b] = x[b] @ W_eff[b] + bout via MFMA, double-buffered LDS W slices.
// grid = NB*256 = 1024 blocks (bid = b*256 + ct*128 + mt), 256 thr.
// Block: 64 tokens x 128 cols. ct-pairs share the x tile on the same XCD.
// ---------------------------------------------------------------------------
__global__ __launch_bounds__(256) void k_out_mfma(
    const float* __restrict__ x, const unsigned short* __restrict__ weffT,
    const float* __restrict__ bout, float* __restrict__ out)
{
  const int tid  = threadIdx.x;
  const int lane = tid & 63;
  const int w    = tid >> 6;
  const int l15  = lane & 15;
  const int lg   = lane >> 4;

  const int bid = blockIdx.x;
  const int mt = bid & 127;
  const int ct = (bid >> 7) & 1;
  const int b  = bid >> 8;
  const int tok0 = mt * 64;
  const int col0 = ct * 128;

  __shared__ unsigned short wsl[2][128 * 36];   // k-slice: 128 cols x 32 k, pad 36

  // A-fragments: x row (tok0 + w*16 + l15), converted fp32->bf16.
  short8 afr[8];
  {
    const float* xr = x + ((size_t)b * NTOK + tok0 + w * 16 + l15) * DIMX + lg * 8;
#pragma unroll
    for (int kk = 0; kk < 8; ++kk) {
      float4 xa = *(const float4*)(xr + kk * 32);
      float4 xb = *(const float4*)(xr + kk * 32 + 4);
      short8 a;
      a[0] = (short)f2bf(xa.x); a[1] = (short)f2bf(xa.y);
      a[2] = (short)f2bf(xa.z); a[3] = (short)f2bf(xa.w);
      a[4] = (short)f2bf(xb.x); a[5] = (short)f2bf(xb.y);
      a[6] = (short)f2bf(xb.z); a[7] = (short)f2bf(xb.w);
      afr[kk] = a;
    }
  }

  f32x4 acc[8];
#pragma unroll
  for (int nf = 0; nf < 8; ++nf) acc[nf] = (f32x4){0.f, 0.f, 0.f, 0.f};

  // staging: thread t stages col (col0 + t>>1), k-half (t&1)*16 of each slice
  const unsigned short* wb = weffT + (size_t)b * DIMX * DIMX
                           + (size_t)(col0 + (tid >> 1)) * DIMX + (tid & 1) * 16;
  const int c36 = (tid >> 1) * 36 + (tid & 1) * 16;

  // prologue: stage slice 0
  *(short8*)&wsl[0][c36]     = *(const short8*)(wb);
  *(short8*)&wsl[0][c36 + 8] = *(const short8*)(wb + 8);
  __syncthreads();

  for (int kk = 0; kk < 8; ++kk) {
    short8 g0, g1;
    if (kk < 7) {
      g0 = *(const short8*)(wb + (kk + 1) * 32);
      g1 = *(const short8*)(wb + (kk + 1) * 32 + 8);
    }
#pragma unroll
    for (int nf = 0; nf < 8; ++nf) {
      short8 b2 = *(const short8*)&wsl[kk & 1][(nf * 16 + l15) * 36 + lg * 8];
      acc[nf] = __builtin_amdgcn_mfma_f32_16x16x32_bf16(afr[kk], b2, acc[nf], 0, 0, 0);
    }
    if (kk < 7) {
      *(short8*)&wsl[(kk + 1) & 1][c36]     = g0;
      *(short8*)&wsl[(kk + 1) & 1][c36 + 8] = g1;
    }
    __syncthreads();
  }

#pragma unroll
  for (int nf = 0; nf < 8; ++nf) {
    const float bias = bout[col0 + nf * 16 + l15];
#pragma unroll
    for (int r = 0; r < 4; ++r) {
      const int row = tok0 + w * 16 + lg * 4 + r;
      out[((size_t)b * NTOK + row) * DIMX + col0 + nf * 16 + l15] = acc[nf][r] + bias;
    }
  }
}

// ---------------------------------------------------------------------------
extern "C" void kernel_launch(void* const* d_in, const int* in_sizes, int n_in,
                              void* d_out, int out_size, void* d_ws, size_t ws_size,
                              hipStream_t stream) {
  const float* x    = (const float*)d_in[0];
  const float* z    = (const float*)d_in[1];
  const float* Wq   = (const float*)d_in[2];
  const float* Wkv  = (const float*)d_in[3];
  const float* Wout = (const float*)d_in[4];
  const float* bout = (const float*)d_in[5];
  float* out = (float*)d_out;

  float* ws  = (float*)d_ws;
  float* tmp = ws;                                            // 524,288 f (2MB)
  unsigned short* wkvT  = (unsigned short*)(tmp + (size_t)NB * INNER * DIMX); // 0.5MB
  unsigned short* weffT = wkvT + (size_t)(2 * INNER) * DIMX;                  // 0.5MB
  // ws total ~3MB

  // d_out is 32MB and fully rewritten by k_out_mfma at the end:
  //  - first 16MB: z in bf16
  //  - next 8MB  : dots split-partials (512 x 4096 f32)
  unsigned short* zbf = (unsigned short*)d_out;
  float* partial = (float*)((char*)d_out + ((size_t)16 << 20));

  k_pre<<<2112, 256, 0, stream>>>(z, zbf, Wkv, wkvT);
  k_dots_mfma<<<NB * NH * SPLIT, 256, 0, stream>>>(zbf, wkvT, partial);
  k_bdwout2<<<NB * 128, 256, 0, stream>>>(partial, Wout, tmp);
  k_weff<<<NB * 128, 256, 0, stream>>>(Wq, tmp, weffT);
  k_out_mfma<<<NB * 256, 256, 0, stream>>>(x, weffT, bout, out);
}